// Round 1
// baseline (314.830 us; speedup 1.0000x reference)
//
#include <hip/hip_runtime.h>

#define E_TOT 500000
#define C_DIM 64
#define K_DIM 320

typedef __attribute__((ext_vector_type(8))) short bf16x8;
typedef __attribute__((ext_vector_type(4))) float f32x4;

__device__ __forceinline__ short f2bf(float f) {
  unsigned u = __float_as_uint(f);
  unsigned r = u + 0x7fffu + ((u >> 16) & 1u);
  return (short)(r >> 16);
}
__device__ __forceinline__ float bf2f(short s) {
  return __uint_as_float(((unsigned)(unsigned short)s) << 16);
}

__global__ __launch_bounds__(512, 2)
void meshconv_kernel(const float* __restrict__ x, const int* __restrict__ nbr,
                     const float* __restrict__ W, const float* __restrict__ bias,
                     float* __restrict__ out) {
  // W fragments, hi/lo bf16, linear per-lane layout:
  // entry fidx = (ks*4 + t)*64 + lane  holds 8 bf16:
  //   W[t*16 + (lane&15)][ks*32 + (lane>>4)*8 + j]
  __shared__ short Whf[20480];
  __shared__ short Wlf[20480];

  const int tid = threadIdx.x;

  // ---- Phase 1: split W (fp32 [64][320]) into bf16 hi/lo fragments in LDS
  for (int fidx = tid; fidx < 2560; fidx += 512) {
    const int l   = fidx & 63;
    const int t   = (fidx >> 6) & 3;
    const int ks  = fidx >> 8;
    const int row = t * 16 + (l & 15);
    const int col = ks * 32 + (l >> 4) * 8;
    const float* src = W + row * K_DIM + col;
    float4 u = *(const float4*)(src);
    float4 v = *(const float4*)(src + 4);
    float f[8] = {u.x, u.y, u.z, u.w, v.x, v.y, v.z, v.w};
    bf16x8 hv, lv;
#pragma unroll
    for (int j = 0; j < 8; ++j) {
      short h = f2bf(f[j]);
      hv[j] = h;
      lv[j] = f2bf(f[j] - bf2f(h));
    }
    *reinterpret_cast<bf16x8*>(&Whf[fidx * 8]) = hv;
    *reinterpret_cast<bf16x8*>(&Wlf[fidx * 8]) = lv;
  }
  __syncthreads();

  const int lane = tid & 63;
  const int wv   = tid >> 6;        // wave in block, 0..7
  const int lrow = lane & 15;       // A-fragment row / D col
  const int kc   = (lane >> 4) * 8; // k-slot base within a 32-wide k-step

  const int base = blockIdx.x * 256 + wv * 32;
  const int e0  = base + lrow;
  const int e1  = base + 16 + lrow;
  const int ec0 = min(e0, E_TOT - 1);
  const int ec1 = min(e1, E_TOT - 1);

  const int4 nb0 = *(const int4*)(nbr + ec0 * 4);
  const int4 nb1 = *(const int4*)(nbr + ec1 * 4);

  f32x4 acc[2][4];
#pragma unroll
  for (int m = 0; m < 2; ++m)
#pragma unroll
    for (int t = 0; t < 4; ++t) acc[m][t] = (f32x4){0.f, 0.f, 0.f, 0.f};

  auto load8 = [&](int row, int h, float* f) {
    const float* p = x + row * C_DIM + h * 32 + kc;
    float4 u = *(const float4*)(p);
    float4 v = *(const float4*)(p + 4);
    f[0] = u.x; f[1] = u.y; f[2] = u.z; f[3] = u.w;
    f[4] = v.x; f[5] = v.y; f[6] = v.z; f[7] = v.w;
  };
  auto cvt = [&](const float* f, bf16x8& hv, bf16x8& lv) {
#pragma unroll
    for (int j = 0; j < 8; ++j) {
      short h = f2bf(f[j]);
      hv[j] = h;
      lv[j] = f2bf(f[j] - bf2f(h));
    }
  };
  auto dot_step = [&](int ks, bf16x8 ah0, bf16x8 al0, bf16x8 ah1, bf16x8 al1) {
#pragma unroll
    for (int t = 0; t < 4; ++t) {
      const int off = ((ks * 4 + t) * 64 + lane) * 8;
      bf16x8 wh = *reinterpret_cast<const bf16x8*>(&Whf[off]);
      bf16x8 wl = *reinterpret_cast<const bf16x8*>(&Wlf[off]);
      acc[0][t] = __builtin_amdgcn_mfma_f32_16x16x32_bf16(ah0, wh, acc[0][t], 0, 0, 0);
      acc[0][t] = __builtin_amdgcn_mfma_f32_16x16x32_bf16(ah0, wl, acc[0][t], 0, 0, 0);
      acc[0][t] = __builtin_amdgcn_mfma_f32_16x16x32_bf16(al0, wh, acc[0][t], 0, 0, 0);
      acc[1][t] = __builtin_amdgcn_mfma_f32_16x16x32_bf16(ah1, wh, acc[1][t], 0, 0, 0);
      acc[1][t] = __builtin_amdgcn_mfma_f32_16x16x32_bf16(ah1, wl, acc[1][t], 0, 0, 0);
      acc[1][t] = __builtin_amdgcn_mfma_f32_16x16x32_bf16(al1, wh, acc[1][t], 0, 0, 0);
    }
  };

  // ---- feature block 0: x itself (k-steps 0..1)
#pragma unroll
  for (int h = 0; h < 2; ++h) {
    float f0[8], f1[8];
    load8(ec0, h, f0);
    load8(ec1, h, f1);
    bf16x8 ah0, al0, ah1, al1;
    cvt(f0, ah0, al0);
    cvt(f1, ah1, al1);
    dot_step(h, ah0, al0, ah1, al1);
  }

  // ---- pair blocks: p=0 -> (nb0,nb1): min@ks2-3, max@ks4-5
  //                   p=1 -> (nb2,nb3): min@ks6-7, max@ks8-9
#pragma unroll
  for (int p = 0; p < 2; ++p) {
    const int nA0 = p ? nb0.z : nb0.x;
    const int nB0 = p ? nb0.w : nb0.y;
    const int nA1 = p ? nb1.z : nb1.x;
    const int nB1 = p ? nb1.w : nb1.y;
#pragma unroll
    for (int h = 0; h < 2; ++h) {
      float fa0[8], fb0[8], fa1[8], fb1[8];
      load8(max(nA0, 0), h, fa0);
      load8(max(nB0, 0), h, fb0);
      load8(max(nA1, 0), h, fa1);
      load8(max(nB1, 0), h, fb1);
      float mn0[8], mx0[8], mn1[8], mx1[8];
#pragma unroll
      for (int j = 0; j < 8; ++j) {
        float a0  = (nA0 < 0) ? 0.f : fa0[j];
        float b0v = (nB0 < 0) ? 0.f : fb0[j];
        float a1  = (nA1 < 0) ? 0.f : fa1[j];
        float b1v = (nB1 < 0) ? 0.f : fb1[j];
        mn0[j] = fminf(a0, b0v);  mx0[j] = fmaxf(a0, b0v);
        mn1[j] = fminf(a1, b1v);  mx1[j] = fmaxf(a1, b1v);
      }
      bf16x8 mnh0, mnl0, mxh0, mxl0, mnh1, mnl1, mxh1, mxl1;
      cvt(mn0, mnh0, mnl0);  cvt(mx0, mxh0, mxl0);
      cvt(mn1, mnh1, mnl1);  cvt(mx1, mxh1, mxl1);
      dot_step(2 + 4 * p + h, mnh0, mnl0, mnh1, mnl1);
      dot_step(4 + 4 * p + h, mxh0, mxl0, mxh1, mxl1);
    }
  }

  // ---- epilogue: bias + store. D layout: col = lane&15, row = (lane>>4)*4 + r
  float bv[4];
#pragma unroll
  for (int t = 0; t < 4; ++t) bv[t] = bias[t * 16 + lrow];

  const int lgrp = lane >> 4;
#pragma unroll
  for (int m = 0; m < 2; ++m)
#pragma unroll
    for (int r = 0; r < 4; ++r) {
      const int e = base + m * 16 + lgrp * 4 + r;
      if (e < E_TOT) {
        float* po = out + e * 64 + lrow;
        po[0]  = acc[m][0][r] + bv[0];
        po[16] = acc[m][1][r] + bv[1];
        po[32] = acc[m][2][r] + bv[2];
        po[48] = acc[m][3][r] + bv[3];
      }
    }
}

extern "C" void kernel_launch(void* const* d_in, const int* in_sizes, int n_in,
                              void* d_out, int out_size, void* d_ws, size_t ws_size,
                              hipStream_t stream) {
  const float* x   = (const float*)d_in[0];
  const int*   nbr = (const int*)d_in[1];
  const float* W   = (const float*)d_in[2];
  const float* b   = (const float*)d_in[3];
  float* out = (float*)d_out;
  const int blocks = (E_TOT + 255) / 256;  // 256 edges per 512-thread block
  hipLaunchKernelGGL(meshconv_kernel, dim3(blocks), dim3(512), 0, stream,
                     x, nbr, W, b, out);
}

// Round 2
// 300.721 us; speedup vs baseline: 1.0469x; 1.0469x over previous
//
#include <hip/hip_runtime.h>

#define E_TOT 500000
#define C_DIM 64
#define K_DIM 320

typedef __attribute__((ext_vector_type(8))) _Float16 half8;
typedef __attribute__((ext_vector_type(4))) float f32x4;

__global__ __launch_bounds__(1024)
void meshconv_kernel(const float* __restrict__ x, const int* __restrict__ nbr,
                     const float* __restrict__ W, const float* __restrict__ bias,
                     float* __restrict__ out) {
  // W fragments, hi/lo fp16, linear per-lane layout:
  // entry fidx = (ks*4 + t)*64 + lane  holds 8 fp16:
  //   W[t*16 + (lane&15)][ks*32 + (lane>>4)*8 + j]
  __shared__ _Float16 Whf[20480];  // 40 KB
  __shared__ _Float16 Wlf[20480];  // 40 KB

  const int tid = threadIdx.x;

  // ---- Phase 1: split W (fp32 [64][320]) into fp16 hi/lo fragments in LDS
  for (int fidx = tid; fidx < 2560; fidx += 1024) {
    const int l   = fidx & 63;
    const int t   = (fidx >> 6) & 3;
    const int ks  = fidx >> 8;
    const int row = t * 16 + (l & 15);
    const int col = ks * 32 + (l >> 4) * 8;
    const float* src = W + row * K_DIM + col;
    float4 u = *(const float4*)(src);
    float4 v = *(const float4*)(src + 4);
    float f[8] = {u.x, u.y, u.z, u.w, v.x, v.y, v.z, v.w};
    half8 hv, lv;
#pragma unroll
    for (int j = 0; j < 8; ++j) {
      _Float16 h = (_Float16)f[j];
      hv[j] = h;
      lv[j] = (_Float16)(f[j] - (float)h);
    }
    *reinterpret_cast<half8*>(&Whf[fidx * 8]) = hv;
    *reinterpret_cast<half8*>(&Wlf[fidx * 8]) = lv;
  }
  __syncthreads();

  const int lane = tid & 63;
  const int wv   = tid >> 6;        // wave in block, 0..15
  const int lrow = lane & 15;       // A-fragment row / D col
  const int kc   = (lane >> 4) * 8; // k-slot base within a 32-wide k-step

  const int base = blockIdx.x * 512 + wv * 32;
  const int e0  = base + lrow;
  const int e1  = base + 16 + lrow;
  const int ec0 = min(e0, E_TOT - 1);
  const int ec1 = min(e1, E_TOT - 1);

  const int4 nb0 = *(const int4*)(nbr + ec0 * 4);
  const int4 nb1 = *(const int4*)(nbr + ec1 * 4);

  f32x4 acc[2][4];
#pragma unroll
  for (int m = 0; m < 2; ++m)
#pragma unroll
    for (int t = 0; t < 4; ++t) acc[m][t] = (f32x4){0.f, 0.f, 0.f, 0.f};

  auto load8 = [&](int row, int h, float* f) {
    const float* p = x + row * C_DIM + h * 32 + kc;
    float4 u = *(const float4*)(p);
    float4 v = *(const float4*)(p + 4);
    f[0] = u.x; f[1] = u.y; f[2] = u.z; f[3] = u.w;
    f[4] = v.x; f[5] = v.y; f[6] = v.z; f[7] = v.w;
  };
  auto cvt = [&](const float* f, half8& hv, half8& lv) {
#pragma unroll
    for (int j = 0; j < 8; ++j) {
      _Float16 h = (_Float16)f[j];
      hv[j] = h;
      lv[j] = (_Float16)(f[j] - (float)h);
    }
  };
  auto dot_step = [&](int ks, half8 ah0, half8 al0, half8 ah1, half8 al1) {
#pragma unroll
    for (int t = 0; t < 4; ++t) {
      const int off = ((ks * 4 + t) * 64 + lane) * 8;
      half8 wh = *reinterpret_cast<const half8*>(&Whf[off]);
      half8 wl = *reinterpret_cast<const half8*>(&Wlf[off]);
      acc[0][t] = __builtin_amdgcn_mfma_f32_16x16x32_f16(ah0, wh, acc[0][t], 0, 0, 0);
      acc[0][t] = __builtin_amdgcn_mfma_f32_16x16x32_f16(ah0, wl, acc[0][t], 0, 0, 0);
      acc[0][t] = __builtin_amdgcn_mfma_f32_16x16x32_f16(al0, wh, acc[0][t], 0, 0, 0);
      acc[1][t] = __builtin_amdgcn_mfma_f32_16x16x32_f16(ah1, wh, acc[1][t], 0, 0, 0);
      acc[1][t] = __builtin_amdgcn_mfma_f32_16x16x32_f16(ah1, wl, acc[1][t], 0, 0, 0);
      acc[1][t] = __builtin_amdgcn_mfma_f32_16x16x32_f16(al1, wh, acc[1][t], 0, 0, 0);
    }
  };

  // ---- feature block 0: x itself (k-steps 0..1)
#pragma unroll
  for (int h = 0; h < 2; ++h) {
    float f0[8], f1[8];
    load8(ec0, h, f0);
    load8(ec1, h, f1);
    half8 ah0, al0, ah1, al1;
    cvt(f0, ah0, al0);
    cvt(f1, ah1, al1);
    dot_step(h, ah0, al0, ah1, al1);
  }

  // ---- pair blocks: p=0 -> (nb0,nb1): min@ks2-3, max@ks4-5
  //                   p=1 -> (nb2,nb3): min@ks6-7, max@ks8-9
#pragma unroll
  for (int p = 0; p < 2; ++p) {
    const int nA0 = p ? nb0.z : nb0.x;
    const int nB0 = p ? nb0.w : nb0.y;
    const int nA1 = p ? nb1.z : nb1.x;
    const int nB1 = p ? nb1.w : nb1.y;
#pragma unroll
    for (int h = 0; h < 2; ++h) {
      float fa0[8], fb0[8], fa1[8], fb1[8];
      load8(max(nA0, 0), h, fa0);
      load8(max(nB0, 0), h, fb0);
      load8(max(nA1, 0), h, fa1);
      load8(max(nB1, 0), h, fb1);
      float mn0[8], mx0[8], mn1[8], mx1[8];
#pragma unroll
      for (int j = 0; j < 8; ++j) {
        float a0  = (nA0 < 0) ? 0.f : fa0[j];
        float b0v = (nB0 < 0) ? 0.f : fb0[j];
        float a1  = (nA1 < 0) ? 0.f : fa1[j];
        float b1v = (nB1 < 0) ? 0.f : fb1[j];
        mn0[j] = fminf(a0, b0v);  mx0[j] = fmaxf(a0, b0v);
        mn1[j] = fminf(a1, b1v);  mx1[j] = fmaxf(a1, b1v);
      }
      half8 mnh0, mnl0, mxh0, mxl0, mnh1, mnl1, mxh1, mxl1;
      cvt(mn0, mnh0, mnl0);  cvt(mx0, mxh0, mxl0);
      cvt(mn1, mnh1, mnl1);  cvt(mx1, mxh1, mxl1);
      dot_step(2 + 4 * p + h, mnh0, mnl0, mnh1, mnl1);
      dot_step(4 + 4 * p + h, mxh0, mxl0, mxh1, mxl1);
    }
  }

  // ---- epilogue: bias + store. D layout: col = lane&15, row = (lane>>4)*4 + r
  float bv[4];
#pragma unroll
  for (int t = 0; t < 4; ++t) bv[t] = bias[t * 16 + lrow];

  const int lgrp = lane >> 4;
#pragma unroll
  for (int m = 0; m < 2; ++m)
#pragma unroll
    for (int r = 0; r < 4; ++r) {
      const int e = base + m * 16 + lgrp * 4 + r;
      if (e < E_TOT) {
        float* po = out + e * 64 + lrow;
        po[0]  = acc[m][0][r] + bv[0];
        po[16] = acc[m][1][r] + bv[1];
        po[32] = acc[m][2][r] + bv[2];
        po[48] = acc[m][3][r] + bv[3];
      }
    }
}

extern "C" void kernel_launch(void* const* d_in, const int* in_sizes, int n_in,
                              void* d_out, int out_size, void* d_ws, size_t ws_size,
                              hipStream_t stream) {
  const float* x   = (const float*)d_in[0];
  const int*   nbr = (const int*)d_in[1];
  const float* W   = (const float*)d_in[2];
  const float* b   = (const float*)d_in[3];
  float* out = (float*)d_out;
  const int blocks = (E_TOT + 511) / 512;  // 512 edges per 1024-thread block
  hipLaunchKernelGGL(meshconv_kernel, dim3(blocks), dim3(1024), 0, stream,
                     x, nbr, W, b, out);
}

// Round 4
// 298.244 us; speedup vs baseline: 1.0556x; 1.0083x over previous
//
#include <hip/hip_runtime.h>

#define E_TOT 500000
#define C_DIM 64

typedef __attribute__((ext_vector_type(8))) _Float16 half8;
typedef __attribute__((ext_vector_type(4))) float f32x4;

// ---- Prologue: x fp32 [E][64] -> x16 fp16 [E][64] (RNE via v_cvt_f16_f32)
__global__ __launch_bounds__(256)
void cvt_x_kernel(const float* __restrict__ x, _Float16* __restrict__ x16) {
  const size_t i = (size_t)blockIdx.x * 256 + threadIdx.x;  // one thread per 8 elems
  const float4* src = (const float4*)x + 2 * i;
  float4 u = src[0], v = src[1];
  half8 h;
  h[0] = (_Float16)u.x; h[1] = (_Float16)u.y; h[2] = (_Float16)u.z; h[3] = (_Float16)u.w;
  h[4] = (_Float16)v.x; h[5] = (_Float16)v.y; h[6] = (_Float16)v.z; h[7] = (_Float16)v.w;
  *((half8*)x16 + i) = h;
}

template <bool USE16>
__global__ __launch_bounds__(512, 4)
void meshconv_main(const float* __restrict__ x, const _Float16* __restrict__ x16,
                   const int* __restrict__ nbr, const float* __restrict__ W,
                   const float* __restrict__ bias, float* __restrict__ out) {
  // W fragments, single fp16, linear per-lane layout (40 KB):
  // frag fidx = (ks*4 + t)*64 + lane holds 8 fp16: W[t*16+(lane&15)][ks*32+(lane>>4)*8+j]
  __shared__ _Float16 Wh[20480];

  const int tid = threadIdx.x;
  for (int fidx = tid; fidx < 2560; fidx += 512) {
    const int l   = fidx & 63;
    const int t   = (fidx >> 6) & 3;
    const int ks  = fidx >> 8;
    const int row = t * 16 + (l & 15);
    const int col = ks * 32 + (l >> 4) * 8;
    const float* src = W + row * 320 + col;
    float4 u = *(const float4*)src;
    float4 v = *(const float4*)(src + 4);
    half8 h;
    h[0] = (_Float16)u.x; h[1] = (_Float16)u.y; h[2] = (_Float16)u.z; h[3] = (_Float16)u.w;
    h[4] = (_Float16)v.x; h[5] = (_Float16)v.y; h[6] = (_Float16)v.z; h[7] = (_Float16)v.w;
    *reinterpret_cast<half8*>(&Wh[fidx * 8]) = h;
  }
  __syncthreads();

  const int lane = tid & 63;
  const int wv   = tid >> 6;         // wave in block, 0..7
  const int lrow = lane & 15;        // A row / D col
  const int kc8  = (lane >> 4) * 8;  // k-slot base within 32-wide k-step

  const int base = blockIdx.x * 256 + wv * 32;
  const int e0  = base + lrow;
  const int e1  = base + 16 + lrow;
  const int ec0 = min(e0, E_TOT - 1);
  const int ec1 = min(e1, E_TOT - 1);

  const int4 nb0 = *(const int4*)(nbr + ec0 * 4);
  const int4 nb1 = *(const int4*)(nbr + ec1 * 4);

  f32x4 acc[2][4];
#pragma unroll
  for (int m = 0; m < 2; ++m)
#pragma unroll
    for (int t = 0; t < 4; ++t) acc[m][t] = (f32x4){0.f, 0.f, 0.f, 0.f};

  // gather one 8-fp16 fragment of row `row`, half `h` (k-cols h*32+kc8 .. +7)
  auto gat = [&](int row, int h) -> half8 {
    if constexpr (USE16) {
      return *reinterpret_cast<const half8*>(x16 + (size_t)row * 64 + h * 32 + kc8);
    } else {
      const float* p = x + (size_t)row * 64 + h * 32 + kc8;
      float4 u = *(const float4*)p;
      float4 v = *(const float4*)(p + 4);
      half8 r;
      r[0] = (_Float16)u.x; r[1] = (_Float16)u.y; r[2] = (_Float16)u.z; r[3] = (_Float16)u.w;
      r[4] = (_Float16)v.x; r[5] = (_Float16)v.y; r[6] = (_Float16)v.z; r[7] = (_Float16)v.w;
      return r;
    }
  };

  // packed min/max with missing-neighbor zeroing (lowers to v_pk_min/max_f16)
  auto mnmx = [&](half8 a, half8 b, int na, int nb_, half8& mn, half8& mx) {
    const half8 zero = (half8)(_Float16)0.0f;
    if (na < 0)  a = zero;
    if (nb_ < 0) b = zero;
    mn = __builtin_elementwise_min(a, b);
    mx = __builtin_elementwise_max(a, b);
  };

  // one k-step: 4 ds_read_b128 of W + 8 MFMAs (both edge-groups)
  auto dot2 = [&](int ks, half8 a0, half8 a1) {
#pragma unroll
    for (int t = 0; t < 4; ++t) {
      half8 w = *reinterpret_cast<const half8*>(&Wh[((ks * 4 + t) * 64 + lane) * 8]);
      acc[0][t] = __builtin_amdgcn_mfma_f32_16x16x32_f16(a0, w, acc[0][t], 0, 0, 0);
      acc[1][t] = __builtin_amdgcn_mfma_f32_16x16x32_f16(a1, w, acc[1][t], 0, 0, 0);
    }
  };

  // ---- issue own-row loads (4) and pair-0 gathers (8)
  const int r0a = max(nb0.x, 0), r0b = max(nb0.y, 0);
  const int r1a = max(nb1.x, 0), r1b = max(nb1.y, 0);
  const int r0c = max(nb0.z, 0), r0d = max(nb0.w, 0);
  const int r1c = max(nb1.z, 0), r1d = max(nb1.w, 0);

  half8 o00 = gat(ec0, 0), o01 = gat(ec0, 1);
  half8 o10 = gat(ec1, 0), o11 = gat(ec1, 1);

  half8 a00 = gat(r0a, 0), b00 = gat(r0b, 0);
  half8 a10 = gat(r1a, 0), b10 = gat(r1b, 0);
  half8 a01 = gat(r0a, 1), b01 = gat(r0b, 1);
  half8 a11 = gat(r1a, 1), b11 = gat(r1b, 1);

  // own-row dots while pair-0 gathers are in flight
  dot2(0, o00, o10);
  dot2(1, o01, o11);

  // ---- issue pair-1 gathers (8) before consuming pair-0
  half8 c00 = gat(r0c, 0), d00 = gat(r0d, 0);
  half8 c10 = gat(r1c, 0), d10 = gat(r1d, 0);
  half8 c01 = gat(r0c, 1), d01 = gat(r0d, 1);
  half8 c11 = gat(r1c, 1), d11 = gat(r1d, 1);

  // ---- pair 0: min @ ks2-3, max @ ks4-5
  {
    half8 mn0, mx0, mn1, mx1;
    mnmx(a00, b00, nb0.x, nb0.y, mn0, mx0);
    mnmx(a10, b10, nb1.x, nb1.y, mn1, mx1);
    dot2(2, mn0, mn1);
    dot2(4, mx0, mx1);
    mnmx(a01, b01, nb0.x, nb0.y, mn0, mx0);
    mnmx(a11, b11, nb1.x, nb1.y, mn1, mx1);
    dot2(3, mn0, mn1);
    dot2(5, mx0, mx1);
  }

  // ---- pair 1: min @ ks6-7, max @ ks8-9
  {
    half8 mn0, mx0, mn1, mx1;
    mnmx(c00, d00, nb0.z, nb0.w, mn0, mx0);
    mnmx(c10, d10, nb1.z, nb1.w, mn1, mx1);
    dot2(6, mn0, mn1);
    dot2(8, mx0, mx1);
    mnmx(c01, d01, nb0.z, nb0.w, mn0, mx0);
    mnmx(c11, d11, nb1.z, nb1.w, mn1, mx1);
    dot2(7, mn0, mn1);
    dot2(9, mx0, mx1);
  }

  // ---- epilogue: bias + store. D layout: col = lane&15, row = (lane>>4)*4 + r
  float bv[4];
#pragma unroll
  for (int t = 0; t < 4; ++t) bv[t] = bias[t * 16 + lrow];

  const int lgrp = lane >> 4;
#pragma unroll
  for (int m = 0; m < 2; ++m)
#pragma unroll
    for (int r = 0; r < 4; ++r) {
      const int e = base + m * 16 + lgrp * 4 + r;
      if (e < E_TOT) {
        float* po = out + (size_t)e * 64 + lrow;
        po[0]  = acc[m][0][r] + bv[0];
        po[16] = acc[m][1][r] + bv[1];
        po[32] = acc[m][2][r] + bv[2];
        po[48] = acc[m][3][r] + bv[3];
      }
    }
}

extern "C" void kernel_launch(void* const* d_in, const int* in_sizes, int n_in,
                              void* d_out, int out_size, void* d_ws, size_t ws_size,
                              hipStream_t stream) {
  const float* x   = (const float*)d_in[0];
  const int*   nbr = (const int*)d_in[1];
  const float* W   = (const float*)d_in[2];
  const float* b   = (const float*)d_in[3];
  float* out = (float*)d_out;

  const int mblocks = (E_TOT + 255) / 256;  // 256 edges per 512-thread block
  const size_t need = (size_t)E_TOT * C_DIM * sizeof(_Float16);  // 64 MB

  if (ws_size >= need) {
    _Float16* x16 = (_Float16*)d_ws;
    const int cblocks = (E_TOT * C_DIM) / (256 * 8);  // 32M elems, 8 per thread
    hipLaunchKernelGGL(cvt_x_kernel, dim3(cblocks), dim3(256), 0, stream, x, x16);
    hipLaunchKernelGGL((meshconv_main<true>), dim3(mblocks), dim3(512), 0, stream,
                       x, x16, nbr, W, b, out);
  } else {
    hipLaunchKernelGGL((meshconv_main<false>), dim3(mblocks), dim3(512), 0, stream,
                       x, (const _Float16*)nullptr, nbr, W, b, out);
  }
}

// Round 5
// 291.796 us; speedup vs baseline: 1.0789x; 1.0221x over previous
//
#include <hip/hip_runtime.h>

#define E_TOT 500000

typedef __attribute__((ext_vector_type(8))) _Float16 half8;
typedef __attribute__((ext_vector_type(4))) float f32x4;

__device__ __forceinline__ half8 cvt8(float4 u, float4 v) {
  half8 h;
  h[0] = (_Float16)u.x; h[1] = (_Float16)u.y; h[2] = (_Float16)u.z; h[3] = (_Float16)u.w;
  h[4] = (_Float16)v.x; h[5] = (_Float16)v.y; h[6] = (_Float16)v.z; h[7] = (_Float16)v.w;
  return h;
}

// ---- Prologue: x fp32 [E][64] -> x16 fp16 [E][64]; block 0 also builds the
// 40 KB fp16 W fragment image (frag f = (ks*4+t)*64+lane holds 8 fp16:
// W[t*16+(lane&15)][ks*32+(lane>>4)*8+j]) so main blocks copy LDS directly.
__global__ __launch_bounds__(256)
void cvt_x_kernel(const float* __restrict__ x, const float* __restrict__ W,
                  _Float16* __restrict__ x16, _Float16* __restrict__ Wfrag) {
  const size_t i = (size_t)blockIdx.x * 256 + threadIdx.x;  // 8 elems / thread
  const float4* src = (const float4*)x + 2 * i;
  *((half8*)x16 + i) = cvt8(src[0], src[1]);
  if (blockIdx.x == 0) {
    for (int f = (int)threadIdx.x; f < 2560; f += 256) {
      const int l = f & 63, t = (f >> 6) & 3, ks = f >> 8;
      const float* s = W + (t * 16 + (l & 15)) * 320 + ks * 32 + (l >> 4) * 8;
      *((half8*)Wfrag + f) = cvt8(*(const float4*)s, *(const float4*)(s + 4));
    }
  }
}

template <bool USE16>
__global__ __launch_bounds__(512, 4)
void meshconv_main(const float* __restrict__ x, const _Float16* __restrict__ x16,
                   const _Float16* __restrict__ Wfrag, const int* __restrict__ nbr,
                   const float* __restrict__ W, const float* __restrict__ bias,
                   float* __restrict__ out) {
  __shared__ _Float16 Wh[20480];  // 40 KB W fragments

  const int tid = threadIdx.x;
  if constexpr (USE16) {
    for (int c = tid; c < 2560; c += 512)
      *reinterpret_cast<half8*>(&Wh[c * 8]) = *((const half8*)Wfrag + c);
  } else {
    for (int f = tid; f < 2560; f += 512) {
      const int l = f & 63, t = (f >> 6) & 3, ks = f >> 8;
      const float* s = W + (t * 16 + (l & 15)) * 320 + ks * 32 + (l >> 4) * 8;
      *reinterpret_cast<half8*>(&Wh[f * 8]) = cvt8(*(const float4*)s, *(const float4*)(s + 4));
    }
  }
  __syncthreads();

  const int lane = tid & 63;
  const int wv   = tid >> 6;         // wave in block, 0..7
  const int eoff = lane & 15;        // edge within a 16-group (B col / D col)
  const int g    = lane >> 4;        // lane group: k-slots on input, ch-quarter on output
  const int kc8  = g * 8;            // k-slot base within 32-wide k-step

  const int base = blockIdx.x * 256 + wv * 32;
  const int e0  = base + eoff;
  const int e1  = base + 16 + eoff;
  const int ec0 = min(e0, E_TOT - 1);
  const int ec1 = min(e1, E_TOT - 1);

  const int4 nb0 = *(const int4*)(nbr + ec0 * 4);
  const int4 nb1 = *(const int4*)(nbr + ec1 * 4);

  f32x4 acc[2][4];
#pragma unroll
  for (int m = 0; m < 2; ++m)
#pragma unroll
    for (int t = 0; t < 4; ++t) acc[m][t] = (f32x4){0.f, 0.f, 0.f, 0.f};

  // gather one 8-fp16 fragment of row `row`, half `h` (k-cols h*32+kc8 .. +7)
  auto gat = [&](int row, int h) -> half8 {
    if constexpr (USE16) {
      return *reinterpret_cast<const half8*>(x16 + (size_t)row * 64 + h * 32 + kc8);
    } else {
      const float* p = x + (size_t)row * 64 + h * 32 + kc8;
      return cvt8(*(const float4*)p, *(const float4*)(p + 4));
    }
  };

  // packed min/max with missing-neighbor zeroing (v_pk_min/max_f16)
  auto mnmx = [&](half8 a, half8 b, int na, int nb_, half8& mn, half8& mx) {
    const half8 zero = (half8)(_Float16)0.0f;
    if (na < 0)  a = zero;
    if (nb_ < 0) b = zero;
    mn = __builtin_elementwise_min(a, b);
    mx = __builtin_elementwise_max(a, b);
  };

  // one k-step: 4 ds_read_b128 of W + 8 MFMAs. A = W tile, B = edge rows.
  // D: row = out-channel (t*16 + g*4 + r), col = edge (eoff).
  auto dot2 = [&](int ks, half8 a0, half8 a1) {
#pragma unroll
    for (int t = 0; t < 4; ++t) {
      half8 w = *reinterpret_cast<const half8*>(&Wh[((ks * 4 + t) * 64 + lane) * 8]);
      acc[0][t] = __builtin_amdgcn_mfma_f32_16x16x32_f16(w, a0, acc[0][t], 0, 0, 0);
      acc[1][t] = __builtin_amdgcn_mfma_f32_16x16x32_f16(w, a1, acc[1][t], 0, 0, 0);
    }
  };

  // ---- issue own-row loads (4) and pair-0 gathers (8)
  const int r0a = max(nb0.x, 0), r0b = max(nb0.y, 0);
  const int r1a = max(nb1.x, 0), r1b = max(nb1.y, 0);
  const int r0c = max(nb0.z, 0), r0d = max(nb0.w, 0);
  const int r1c = max(nb1.z, 0), r1d = max(nb1.w, 0);

  half8 o00 = gat(ec0, 0), o01 = gat(ec0, 1);
  half8 o10 = gat(ec1, 0), o11 = gat(ec1, 1);

  half8 a00 = gat(r0a, 0), b00 = gat(r0b, 0);
  half8 a10 = gat(r1a, 0), b10 = gat(r1b, 0);
  half8 a01 = gat(r0a, 1), b01 = gat(r0b, 1);
  half8 a11 = gat(r1a, 1), b11 = gat(r1b, 1);

  // own-row dots while pair-0 gathers are in flight
  dot2(0, o00, o10);
  dot2(1, o01, o11);

  // ---- issue pair-1 gathers (8) before consuming pair-0
  half8 c00 = gat(r0c, 0), d00 = gat(r0d, 0);
  half8 c10 = gat(r1c, 0), d10 = gat(r1d, 0);
  half8 c01 = gat(r0c, 1), d01 = gat(r0d, 1);
  half8 c11 = gat(r1c, 1), d11 = gat(r1d, 1);

  // ---- pair 0: min @ ks2-3, max @ ks4-5
  {
    half8 mn0, mx0, mn1, mx1;
    mnmx(a00, b00, nb0.x, nb0.y, mn0, mx0);
    mnmx(a10, b10, nb1.x, nb1.y, mn1, mx1);
    dot2(2, mn0, mn1);
    dot2(4, mx0, mx1);
    mnmx(a01, b01, nb0.x, nb0.y, mn0, mx0);
    mnmx(a11, b11, nb1.x, nb1.y, mn1, mx1);
    dot2(3, mn0, mn1);
    dot2(5, mx0, mx1);
  }

  // ---- pair 1: min @ ks6-7, max @ ks8-9
  {
    half8 mn0, mx0, mn1, mx1;
    mnmx(c00, d00, nb0.z, nb0.w, mn0, mx0);
    mnmx(c10, d10, nb1.z, nb1.w, mn1, mx1);
    dot2(6, mn0, mn1);
    dot2(8, mx0, mx1);
    mnmx(c01, d01, nb0.z, nb0.w, mn0, mx0);
    mnmx(c11, d11, nb1.z, nb1.w, mn1, mx1);
    dot2(7, mn0, mn1);
    dot2(9, mx0, mx1);
  }

  // ---- epilogue: bias + contiguous dwordx4 stores.
  // lane holds channels t*16 + g*4 .. +3 (acc[m][t][r]) of edge base + m*16 + eoff.
  f32x4 bv[4];
#pragma unroll
  for (int t = 0; t < 4; ++t) bv[t] = *(const f32x4*)(bias + t * 16 + g * 4);

#pragma unroll
  for (int m = 0; m < 2; ++m) {
    const int e = base + m * 16 + eoff;
    if (e < E_TOT) {
      float* po = out + (size_t)e * 64 + g * 4;
#pragma unroll
      for (int t = 0; t < 4; ++t) {
        *(f32x4*)(po + t * 16) = acc[m][t] + bv[t];
      }
    }
  }
}

extern "C" void kernel_launch(void* const* d_in, const int* in_sizes, int n_in,
                              void* d_out, int out_size, void* d_ws, size_t ws_size,
                              hipStream_t stream) {
  const float* x   = (const float*)d_in[0];
  const int*   nbr = (const int*)d_in[1];
  const float* W   = (const float*)d_in[2];
  const float* b   = (const float*)d_in[3];
  float* out = (float*)d_out;

  const int mblocks = (E_TOT + 255) / 256;  // 256 edges per 512-thread block
  const size_t x16_bytes = (size_t)E_TOT * 64 * sizeof(_Float16);  // 64 MB
  const size_t need = x16_bytes + 2560 * 8 * sizeof(_Float16);     // + 40 KB

  if (ws_size >= need) {
    _Float16* x16   = (_Float16*)d_ws;
    _Float16* Wfrag = (_Float16*)((char*)d_ws + x16_bytes);
    const int cblocks = (E_TOT * 64) / (256 * 8);  // 15625
    hipLaunchKernelGGL(cvt_x_kernel, dim3(cblocks), dim3(256), 0, stream,
                       x, W, x16, Wfrag);
    hipLaunchKernelGGL((meshconv_main<true>), dim3(mblocks), dim3(512), 0, stream,
                       x, x16, Wfrag, nbr, W, b, out);
  } else {
    hipLaunchKernelGGL((meshconv_main<false>), dim3(mblocks), dim3(512), 0, stream,
                       x, (const _Float16*)nullptr, (const _Float16*)nullptr,
                       nbr, W, b, out);
  }
}